// Round 10
// baseline (288.370 us; speedup 1.0000x reference)
//
#include <hip/hip_runtime.h>

#define EPS 1e-5f

// Problem dims (fixed by setup_inputs)
constexpr int T  = 512;
constexpr int B  = 64;
constexpr int HU = 1024;
constexpr int S  = 1024;
constexpr int C  = B * HU;       // 65536 (b,hu) columns
constexpr int NSLAB = 64;        // one part slab per wave-owned 8-t group

// ws layout (in floats); high-water ~17 MB
constexpr size_t OFF_SIW0 = 0;            // [64][10]
constexpr size_t OFF_W    = 1024;         // [512]    e^{s_tau}, tau<512
constexpr size_t OFF_ESC  = 2048;         // [32768]  e^{s} for ALL (t,b) -> Z
constexpr size_t OFF_W0T  = 34816;        // [10][1024] transposed h-half of W0
constexpr size_t OFF_PART = 45056;        // [64][65536] per-8t-group partials

// ---------------------------------------------------------------------------
// MLP head (10 -> 5 -> 1)
// ---------------------------------------------------------------------------
__device__ __forceinline__ float mlp_head(
    const float* __restrict__ u10,
    const float* __restrict__ b0, const float* __restrict__ g0,
    const float* __restrict__ be0,const float* __restrict__ m0,
    const float* __restrict__ v0,
    const float* __restrict__ W1, const float* __restrict__ b1,
    const float* __restrict__ g1, const float* __restrict__ be1,
    const float* __restrict__ m1, const float* __restrict__ v1,
    const float* __restrict__ W2, const float* __restrict__ b2) {
    float y[10];
#pragma unroll
    for (int j = 0; j < 10; ++j) {
        float u = (u10[j] + b0[j] - m0[j]) * (1.0f / sqrtf(v0[j] + EPS)) * g0[j]
                  + be0[j];
        y[j] = fmaxf(u, 0.f);
    }
    float z[5];
#pragma unroll
    for (int i = 0; i < 5; ++i) {
        float u = b1[i];
#pragma unroll
        for (int j = 0; j < 10; ++j) u = fmaf(y[j], W1[j * 5 + i], u);
        u = (u - m1[i]) * (1.0f / sqrtf(v1[i] + EPS)) * g1[i] + be1[i];
        z[i] = fmaxf(u, 0.f);
    }
    float sc = b2[0];
#pragma unroll
    for (int i = 0; i < 5; ++i) sc = fmaf(z[i], W2[i], sc);
    return sc;
}

// ---------------------------------------------------------------------------
// k_tr: W0T[j][k] = W0[1024+k][j]  (one block; reads 40B/thread contiguous,
// writes coalesced across threads per j). ~1-2 us.
// ---------------------------------------------------------------------------
__global__ __launch_bounds__(1024) void k_tr(const float* __restrict__ W0,
                                             float* __restrict__ W0T) {
    const int k = threadIdx.x;           // 0..1023
    const float* src = W0 + (size_t)(1024 + k) * 10;   // 40B, 8B-aligned
    float v[10];
#pragma unroll
    for (int q = 0; q < 5; ++q) {
        const float2 p = ((const float2*)src)[q];
        v[2 * q] = p.x; v[2 * q + 1] = p.y;
    }
#pragma unroll
    for (int j = 0; j < 10; ++j) W0T[j * 1024 + k] = v[j];
}

// ---------------------------------------------------------------------------
// kA: the 512 USED weights w[tau] = e^{s(t,b)}, tau = t*64+b, t<8.
// Blocks with t==0 also export siW0[b][10]. (Proven r5..r9 — unchanged.)
// ---------------------------------------------------------------------------
__global__ __launch_bounds__(256) void k_weights(
    const float* __restrict__ h,  const float* __restrict__ si,
    const float* __restrict__ W0,
    const float* __restrict__ b0, const float* __restrict__ g0,
    const float* __restrict__ be0,const float* __restrict__ m0,
    const float* __restrict__ v0,
    const float* __restrict__ W1, const float* __restrict__ b1,
    const float* __restrict__ g1, const float* __restrict__ be1,
    const float* __restrict__ m1, const float* __restrict__ v1,
    const float* __restrict__ W2, const float* __restrict__ b2,
    float* __restrict__ w, float* __restrict__ siW0out) {
    const int e   = blockIdx.x;
    const int t   = e >> 6;              // 0..7
    const int cb  = e & 63;              // b
    const int tid = threadIdx.x;
    const int wv  = tid >> 6, ln = tid & 63;

    const float4 hv = *(const float4*)(h  + (size_t)t  * C + (size_t)cb * HU + tid * 4);
    const float4 sv = *(const float4*)(si + (size_t)cb * S + tid * 4);
    const float* wsb = W0 + (size_t)(4 * tid) * 10;          // si half rows
    const float* whb = W0 + (size_t)(1024 + 4 * tid) * 10;   // h half rows

    float ssi[10], shh[10];
#pragma unroll
    for (int j = 0; j < 10; ++j) { ssi[j] = 0.f; shh[j] = 0.f; }
#pragma unroll
    for (int d = 0; d < 4; ++d) {
        const float sx = (&sv.x)[d], hx = (&hv.x)[d];
#pragma unroll
        for (int j = 0; j < 10; ++j) {
            ssi[j] = fmaf(sx, wsb[d * 10 + j], ssi[j]);
            shh[j] = fmaf(hx, whb[d * 10 + j], shh[j]);
        }
    }
#pragma unroll
    for (int j = 0; j < 10; ++j) {
#pragma unroll
        for (int off = 32; off > 0; off >>= 1) {
            ssi[j] += __shfl_down(ssi[j], off, 64);
            shh[j] += __shfl_down(shh[j], off, 64);
        }
    }
    __shared__ float rs[4][10], rh[4][10];
    if (ln == 0) {
#pragma unroll
        for (int j = 0; j < 10; ++j) { rs[wv][j] = ssi[j]; rh[wv][j] = shh[j]; }
    }
    __syncthreads();

    if (t == 0 && tid < 10)
        siW0out[cb * 10 + tid] = rs[0][tid] + rs[1][tid] + rs[2][tid] + rs[3][tid];

    if (tid == 0) {
        float u10[10];
#pragma unroll
        for (int j = 0; j < 10; ++j)
            u10[j] = rs[0][j] + rs[1][j] + rs[2][j] + rs[3][j] +
                     rh[0][j] + rh[1][j] + rh[2][j] + rh[3][j];
        const float sc = mlp_head(u10, b0, g0, be0, m0, v0,
                                  W1, b1, g1, be1, m1, v1, W2, b2);
        w[t * 64 + cb] = expf(sc);   // |sc| BN-bounded -> no max-sub needed
    }
}

// ---------------------------------------------------------------------------
// k_stream: BARRIER-FREE single h pass doing BOTH scores and weighted sums.
// Grid 1024 blocks x 256 thr (4 waves) = 16 waves/CU, 4 blocks/CU.
// Block (tg,b); wave wv owns 8 consecutive t's: t0 = 32tg + 8wv, one b.
// Lane ln covers k = 64s + ln (coalesced h AND W0T reads). Per strip s:
//   w0t[j] = W0T[j][k]  (10 coalesced loads, L1/L2-hot, reused x4 rows)
//   per row r: hx = h[t][b][k]; sacc[r][j] += hx*w0t[j]; acc[s] += w[t]*hx.
// Rows done in 2 passes of 4 (caps VGPR ~85). Row end: butterfly-reduce
// sacc across 64 lanes (all-lanes), + siW0 -> head -> lane0 writes escore.
// Wave writes its own part slab (no cross-wave combine). NO LDS, NO barriers.
// ---------------------------------------------------------------------------
__global__ __launch_bounds__(256, 4) void k_stream(
    const float* __restrict__ h,  const float* __restrict__ W0T,
    const float* __restrict__ w,  const float* __restrict__ siW0,
    const float* __restrict__ b0, const float* __restrict__ g0,
    const float* __restrict__ be0,const float* __restrict__ m0,
    const float* __restrict__ v0,
    const float* __restrict__ W1, const float* __restrict__ b1,
    const float* __restrict__ g1, const float* __restrict__ be1,
    const float* __restrict__ m1, const float* __restrict__ v1,
    const float* __restrict__ W2, const float* __restrict__ b2,
    float* __restrict__ escore, float* __restrict__ part) {
    const int b    = blockIdx.x & 63;
    const int tg   = blockIdx.x >> 6;        // 0..15
    const int wv   = threadIdx.x >> 6;       // 0..3
    const int ln   = threadIdx.x & 63;
    const int t0   = tg * 32 + wv * 8;       // wave's 8 t's
    const int slab = tg * 4 + wv;            // 0..63

    float acc[16];
#pragma unroll
    for (int s = 0; s < 16; ++s) acc[s] = 0.f;

#pragma unroll
    for (int pass = 0; pass < 2; ++pass) {
        const int tA = t0 + pass * 4;
        const float* hp = h + ((size_t)tA * 64 + b) * HU;  // row stride 64*HU
        const float wt0 = w[tA + 0], wt1 = w[tA + 1];      // uniform -> s_load
        const float wt2 = w[tA + 2], wt3 = w[tA + 3];

        float sacc[4][10];
#pragma unroll
        for (int r = 0; r < 4; ++r)
#pragma unroll
            for (int j = 0; j < 10; ++j) sacc[r][j] = 0.f;

#pragma unroll 4
        for (int s = 0; s < 16; ++s) {
            const int k = 64 * s + ln;
            float w0t[10];
#pragma unroll
            for (int j = 0; j < 10; ++j) w0t[j] = W0T[j * 1024 + k];

            const float hx0 = hp[k];
            const float hx1 = hp[(size_t)1 * 64 * HU + k];
            const float hx2 = hp[(size_t)2 * 64 * HU + k];
            const float hx3 = hp[(size_t)3 * 64 * HU + k];
#pragma unroll
            for (int j = 0; j < 10; ++j) {
                sacc[0][j] = fmaf(hx0, w0t[j], sacc[0][j]);
                sacc[1][j] = fmaf(hx1, w0t[j], sacc[1][j]);
                sacc[2][j] = fmaf(hx2, w0t[j], sacc[2][j]);
                sacc[3][j] = fmaf(hx3, w0t[j], sacc[3][j]);
            }
            acc[s] = fmaf(wt0, hx0, acc[s]);
            acc[s] = fmaf(wt1, hx1, acc[s]);
            acc[s] = fmaf(wt2, hx2, acc[s]);
            acc[s] = fmaf(wt3, hx3, acc[s]);
        }

        // row epilogues: butterfly reduce (all lanes), head, lane0 stores
#pragma unroll
        for (int r = 0; r < 4; ++r) {
            float u10[10];
#pragma unroll
            for (int j = 0; j < 10; ++j) {
                float v = sacc[r][j];
#pragma unroll
                for (int off = 32; off > 0; off >>= 1)
                    v += __shfl_xor(v, off, 64);
                u10[j] = v + siW0[b * 10 + j];
            }
            const float sc = mlp_head(u10, b0, g0, be0, m0, v0,
                                      W1, b1, g1, be1, m1, v1, W2, b2);
            if (ln == 0)
                escore[(size_t)(tA + r) * 64 + b] = expf(sc);
        }
    }

    // weighted-sum slab: coalesced, wave-private -> no reduction needed
    float* pp = part + (size_t)slab * C + (size_t)b * HU;
#pragma unroll
    for (int s = 0; s < 16; ++s) pp[64 * s + ln] = acc[s];
}

// ---------------------------------------------------------------------------
// kC: Z = sum(escore) (redundant per block, L2-hot), then
// out[c] = (1/Z) * sum_{64 slabs} part[sl][c].  Grid 64 x 256 threads.
// ---------------------------------------------------------------------------
__global__ __launch_bounds__(256) void k_out(const float* __restrict__ part,
                                             const float* __restrict__ escore,
                                             float* __restrict__ out) {
    const int tid = threadIdx.x;
    const int wv  = tid >> 6, ln = tid & 63;

    float zs = 0.f;
#pragma unroll
    for (int q = 0; q < 32; ++q) {
        const float4 v = ((const float4*)escore)[tid + 256 * q];
        zs += v.x + v.y + v.z + v.w;
    }
#pragma unroll
    for (int off = 32; off > 0; off >>= 1)
        zs += __shfl_down(zs, off, 64);
    __shared__ float zr[4];
    __shared__ float sinv;
    if (ln == 0) zr[wv] = zs;
    __syncthreads();
    if (tid == 0) sinv = 1.0f / (zr[0] + zr[1] + zr[2] + zr[3]);
    __syncthreads();
    const float invZ = sinv;

    const int c = blockIdx.x * 1024 + tid * 4;
    float4 s = {0.f, 0.f, 0.f, 0.f};
#pragma unroll 8
    for (int sl = 0; sl < NSLAB; ++sl) {
        const float4 v = *(const float4*)(part + (size_t)sl * C + c);
        s.x += v.x; s.y += v.y; s.z += v.z; s.w += v.w;
    }
    s.x *= invZ; s.y *= invZ; s.z *= invZ; s.w *= invZ;
    *(float4*)(out + c) = s;
}

// ---------------------------------------------------------------------------
extern "C" void kernel_launch(void* const* d_in, const int* in_sizes, int n_in,
                              void* d_out, int out_size, void* d_ws, size_t ws_size,
                              hipStream_t stream) {
    const float* si  = (const float*)d_in[0];
    const float* h   = (const float*)d_in[1];
    const float* W0  = (const float*)d_in[2];
    const float* b0  = (const float*)d_in[3];
    const float* g0  = (const float*)d_in[4];
    const float* be0 = (const float*)d_in[5];
    const float* m0  = (const float*)d_in[6];
    const float* v0  = (const float*)d_in[7];
    const float* W1  = (const float*)d_in[8];
    const float* b1  = (const float*)d_in[9];
    const float* g1  = (const float*)d_in[10];
    const float* be1 = (const float*)d_in[11];
    const float* m1  = (const float*)d_in[12];
    const float* v1  = (const float*)d_in[13];
    const float* W2  = (const float*)d_in[14];
    const float* b2  = (const float*)d_in[15];

    float* ws     = (float*)d_ws;
    float* siW0   = ws + OFF_SIW0;
    float* w      = ws + OFF_W;
    float* escore = ws + OFF_ESC;
    float* W0T    = ws + OFF_W0T;
    float* part   = ws + OFF_PART;
    float* out    = (float*)d_out;

    hipLaunchKernelGGL(k_tr,      dim3(1),    dim3(1024), 0, stream, W0, W0T);
    hipLaunchKernelGGL(k_weights, dim3(512),  dim3(256),  0, stream, h, si, W0,
                       b0, g0, be0, m0, v0, W1, b1, g1, be1, m1, v1, W2, b2,
                       w, siW0);
    hipLaunchKernelGGL(k_stream,  dim3(1024), dim3(256),  0, stream, h, W0T, w,
                       siW0, b0, g0, be0, m0, v0, W1, b1, g1, be1, m1, v1,
                       W2, b2, escore, part);
    hipLaunchKernelGGL(k_out,     dim3(64),   dim3(256),  0, stream, part,
                       escore, out);
}